// Round 8
// baseline (976.191 us; speedup 1.0000x reference)
//
#include <hip/hip_runtime.h>
#include <math.h>

// GARNN: graph-attention GRU, B=16, N=512, U=64, SEQ=12, HORIZON=12, all f32.
// R8 = R7 (XCD swizzle, 802us) + batch-pair waves: each wave handles node i for
// BOTH batches of its XCD's pair {2x, 2x+1}. Grid 1024->512 blocks => fully
// resident in one round (3 blk/CU x 256 CU = 768 slots); idx/softmax-shuffle/
// LDS-weight traffic amortized 2x; dual-node ILP in gather+GEMV. Load depth
// stays 16 in flight (8 per batch). launch_bounds(512,6) (VGPR cap ~84).

#define NB 16
#define NN 512
#define NU 64
#define CAP 128   // neighbor-list capacity
#define WPB 8     // waves per block; wave = 1 node-row, batch pair

#define AS1 __attribute__((address_space(1)))
#define AS3 __attribute__((address_space(3)))

__device__ __forceinline__ void ld_lds16(float* lds_uniform, const float* g_perlane) {
#if __has_builtin(__builtin_amdgcn_global_load_lds)
  __builtin_amdgcn_global_load_lds((const AS1 unsigned int*)g_perlane,
                                   (AS3 unsigned int*)lds_uniform, 16, 0, 0);
#else
  int lane = threadIdx.x & 63;
  *(float4*)(lds_uniform + lane * 4) = *(const float4*)(g_perlane);
#endif
}

__device__ __forceinline__ void stage_weights(float* sW, const float* W, int TB,
                                              int w, int lane) {
  for (int c = w; c * 1024 < TB; c += WPB) {
    int off = c * 1024 + lane * 16;
    if (off < TB)
      ld_lds16((float*)((char*)sW + c * 1024), (const float*)((const char*)W + off));
  }
}

__device__ __forceinline__ float rlane(float v, int l) {
  return __int_as_float(__builtin_amdgcn_readlane(__float_as_int(v), l));
}
__device__ __forceinline__ int rlane_i(int v, int l) {
  return __builtin_amdgcn_readlane(v, l);
}
__device__ __forceinline__ void wave_max2(float& x, float& y) {
  #pragma unroll
  for (int s = 1; s < 64; s <<= 1) {
    x = fmaxf(x, __shfl_xor(x, s));
    y = fmaxf(y, __shfl_xor(y, s));
  }
}
__device__ __forceinline__ void wave_sum2(float& x, float& y) {
  #pragma unroll
  for (int s = 1; s < 64; s <<= 1) { x += __shfl_xor(x, s); y += __shfl_xor(y, s); }
}
__device__ __forceinline__ void wave_sum4(float& a, float& b, float& c, float& d) {
  #pragma unroll
  for (int s = 1; s < 64; s <<= 1) {
    a += __shfl_xor(a, s); b += __shfl_xor(b, s);
    c += __shfl_xor(c, s); d += __shfl_xor(d, s);
  }
}
__device__ __forceinline__ float fast_rcp(float x) {
#if __has_builtin(__builtin_amdgcn_rcpf)
  return __builtin_amdgcn_rcpf(x);
#else
  return 1.0f / x;
#endif
}
__device__ __forceinline__ float sigmoid_f(float x) {
  return fast_rcp(1.0f + __expf(-x));
}
__device__ __forceinline__ float tanh_f(float x) {
  return 1.0f - 2.0f * fast_rcp(__expf(2.0f * x) + 1.0f);
}

// Decode: blockIdx%8 = XCD (dispatch heuristic); XCD x owns batch pair {2x,2x+1}.
// k = blockIdx>>3 in [0,64) is the node chunk; i = k*8 + wave.
__device__ __forceinline__ void decode_block(int bx, int w, int& b0, int& i) {
  b0 = (bx & 7) << 1;
  i = (((bx >> 3)) << 3) | w;
}

// Neighbor lists: mask[i][j] = adj[i][j] > 0.9 || i == j, ascending j.
// Pad tail [cnt, CAP) with j=i so gather loops run unpredicated (p=0 there).
__global__ __launch_bounds__(64) void k_adj(const float* __restrict__ adj,
                                            int* __restrict__ cnt,
                                            int* __restrict__ idx) {
  int i = blockIdx.x;
  int l = threadIdx.x;
  int base = 0;
  #pragma unroll
  for (int c = 0; c < 8; ++c) {
    int j = c * 64 + l;
    bool pred = (adj[i * NN + j] > 0.9f) || (j == i);
    unsigned long long m = __ballot(pred);
    int pos = base + __popcll(m & ((1ull << l) - 1ull));
    if (pred && pos < CAP) idx[i * CAP + pos] = j;
    base += __popcll(m);
  }
  int total = base > CAP ? CAP : base;
  for (int p = total + l; p < CAP; p += 64) idx[i * CAP + p] = i;  // pad
  if (l == 0) cnt[i] = total;
}

// Phase B: ru-attention -> r,u ; write u; h_c = [x, r*h] @ W_c; src_c/dst_c.
// One wave per node i, batch pair (b0, b0+1).
template <int DIN>
__global__ __launch_bounds__(512, 6) void k_phaseB(
    const int* __restrict__ cnt, const int* __restrict__ idx,
    const float* __restrict__ h_ru, const float* __restrict__ src_ru,
    const float* __restrict__ dst_ru, const float* __restrict__ b_ru,
    const float* __restrict__ h, const float* __restrict__ x_ptr,
    const float* __restrict__ W_c, const float* __restrict__ a_c,
    float* __restrict__ h_c, float* __restrict__ src_c,
    float* __restrict__ dst_c, float* __restrict__ u_buf) {
  constexpr int TB = (DIN + NU) * NU * 4;
  __shared__ float sW[(DIN + NU) * NU];
  __shared__ float sh[WPB * 2 * NU];    // per-wave r*h broadcast, 2 nodes
  const int tid = threadIdx.x;
  const int w = tid >> 6, lane = tid & 63;

  stage_weights(sW, W_c, TB, w, lane);   // async; drained at the barrier below

  int b0, i;
  decode_block(blockIdx.x, w, b0, i);
  const int bi0 = (b0 << 9) + i, bi1 = bi0 + NN;
  const float* __restrict__ hrb0 = h_ru + ((size_t)b0 << 16);
  const float* __restrict__ drb0 = dst_ru + (b0 << 9);

  const int c_ = cnt[i];
  const int j0 = idx[(i << 7) + lane];
  const int j1 = idx[(i << 7) + 64 + lane];
  const float si0 = src_ru[bi0], si1 = src_ru[bi1];
  float e00 = -1e30f, e01 = -1e30f, e10 = -1e30f, e11 = -1e30f;
  if (lane < c_) {
    float t0 = si0 + drb0[j0];      e00 = t0 >= 0.f ? t0 : 0.2f * t0;
    float t1 = si1 + drb0[NN + j0]; e10 = t1 >= 0.f ? t1 : 0.2f * t1;
  }
  if (lane + 64 < c_) {
    float t0 = si0 + drb0[j1];      e01 = t0 >= 0.f ? t0 : 0.2f * t0;
    float t1 = si1 + drb0[NN + j1]; e11 = t1 >= 0.f ? t1 : 0.2f * t1;
  }
  float m0 = fmaxf(e00, e01), m1 = fmaxf(e10, e11);
  wave_max2(m0, m1);
  float p00 = (lane < c_)      ? __expf(e00 - m0) : 0.f;
  float p01 = (lane + 64 < c_) ? __expf(e01 - m0) : 0.f;
  float p10 = (lane < c_)      ? __expf(e10 - m1) : 0.f;
  float p11 = (lane + 64 < c_) ? __expf(e11 - m1) : 0.f;
  float s0 = p00 + p01, s1 = p10 + p11;
  wave_sum2(s0, s1);
  float inv0 = fast_rcp(s0), inv1 = fast_rcp(s1);
  p00 *= inv0; p01 *= inv0; p10 *= inv1; p11 *= inv1;

  // gather: 8 neighbors per group x 2 batches = 16 loads in flight.
  const int g0 = lane << 1;
  float A00 = 0.f, A01 = 0.f, A10 = 0.f, A11 = 0.f;
  const int ccn = (c_ + 7) & ~7;
  for (int base = 0; base < ccn; base += 8) {
    float2 hv0[8], hv1[8];
    #pragma unroll
    for (int q = 0; q < 8; ++q) {
      int jj = base + q; int sl = jj & 63;
      int j = (jj < 64) ? rlane_i(j0, sl) : rlane_i(j1, sl);
      const float* p = hrb0 + (j << 7) + g0;
      hv0[q] = *(const float2*)p;
      hv1[q] = *(const float2*)(p + (1 << 16));
    }
    #pragma unroll
    for (int q = 0; q < 8; ++q) {
      int jj = base + q; int sl = jj & 63;
      float pv0 = (jj < 64) ? rlane(p00, sl) : rlane(p01, sl);
      float pv1 = (jj < 64) ? rlane(p10, sl) : rlane(p11, sl);
      A00 = fmaf(pv0, hv0[q].x, A00); A01 = fmaf(pv0, hv0[q].y, A01);
      A10 = fmaf(pv1, hv1[q].x, A10); A11 = fmaf(pv1, hv1[q].y, A11);
    }
  }

  const float2 br = *(const float2*)(b_ru + g0);
  const float ru00 = sigmoid_f(A00 + br.x), ru01 = sigmoid_f(A01 + br.y);
  const float ru10 = sigmoid_f(A10 + br.x), ru11 = sigmoid_f(A11 + br.y);

  // lanes 0..31: r (g<64) -> r*h into LDS; lanes 32..63: u -> global
  if (lane < 32) {
    float2 hh0 = *(const float2*)(h + ((size_t)bi0 << 6) + g0);
    float2 hh1 = *(const float2*)(h + ((size_t)bi1 << 6) + g0);
    *(float2*)&sh[(w << 7) + g0]      = make_float2(ru00 * hh0.x, ru01 * hh0.y);
    *(float2*)&sh[(w << 7) + 64 + g0] = make_float2(ru10 * hh1.x, ru11 * hh1.y);
  } else {
    *(float2*)(u_buf + ((size_t)bi0 << 6) + (g0 - 64)) = make_float2(ru00, ru01);
    *(float2*)(u_buf + ((size_t)bi1 << 6) + (g0 - 64)) = make_float2(ru10, ru11);
  }

  __syncthreads();   // drains async weight stage; sh is wave-private

  // h_c GEMV over xc = [x, r*h]; output feature = lane; weights shared 2 nodes
  float acc0, acc1;
  if (DIN == 2) {
    float2 xv0 = *(const float2*)(x_ptr + ((size_t)bi0 << 1));
    float2 xv1 = *(const float2*)(x_ptr + ((size_t)bi1 << 1));
    acc0 = xv0.x * sW[lane]; acc0 = fmaf(xv0.y, sW[NU + lane], acc0);
    acc1 = xv1.x * sW[lane]; acc1 = fmaf(xv1.y, sW[NU + lane], acc1);
  } else {
    acc0 = x_ptr[bi0] * sW[lane];
    acc1 = x_ptr[bi1] * sW[lane];
  }
  const float* __restrict__ sWh = sW + DIN * NU;
  const float* shw0 = sh + (w << 7);
  const float* shw1 = shw0 + 64;
  #pragma unroll
  for (int f2 = 0; f2 < 32; ++f2) {
    float2 rv0 = *(const float2*)(shw0 + 2 * f2);
    float2 rv1 = *(const float2*)(shw1 + 2 * f2);
    float w0 = sWh[(2 * f2) * NU + lane];
    float w1 = sWh[(2 * f2 + 1) * NU + lane];
    acc0 = fmaf(rv0.x, w0, acc0); acc0 = fmaf(rv0.y, w1, acc0);
    acc1 = fmaf(rv1.x, w0, acc1); acc1 = fmaf(rv1.y, w1, acc1);
  }
  h_c[((size_t)bi0 << 6) + lane] = acc0;
  h_c[((size_t)bi1 << 6) + lane] = acc1;
  float s00 = acc0 * a_c[lane], s01 = acc0 * a_c[NU + lane];
  float s10 = acc1 * a_c[lane], s11 = acc1 * a_c[NU + lane];
  wave_sum4(s00, s01, s10, s11);
  if (lane == 0) {
    src_c[bi0] = s00; dst_c[bi0] = s01;
    src_c[bi1] = s10; dst_c[bi1] = s11;
  }
}

// Phase A: c-attention -> c; h_new = u*h + (1-u)*c (UPD) or 0 (init);
// OUT: proj -> out+y_buf; DIN_NEXT>0: next cell h_ru = [x_next, h_new] @ W_ru.
template <int UPD, int DIN_NEXT, int XMODE, int OUT>
__global__ __launch_bounds__(512, 6) void k_phaseA(
    const int* __restrict__ cnt, const int* __restrict__ idx,
    const float* __restrict__ h_c, const float* __restrict__ src_c,
    const float* __restrict__ dst_c, const float* __restrict__ b_c,
    const float* __restrict__ u_buf, float* __restrict__ h,
    const float* __restrict__ proj_W, const float* __restrict__ proj_b,
    float* __restrict__ out_slice, float* __restrict__ y_buf,
    const float* __restrict__ x_ptr,
    const float* __restrict__ W_ru, const float* __restrict__ a_ru,
    float* __restrict__ h_ru, float* __restrict__ src_ru,
    float* __restrict__ dst_ru) {
  constexpr int SWN = (DIN_NEXT > 0) ? (DIN_NEXT + NU) * 128 : 1;
  constexpr int TB = (DIN_NEXT > 0) ? SWN * 4 : 0;
  __shared__ float sW[SWN];
  __shared__ float sh[WPB * 2 * NU];
  const int tid = threadIdx.x;
  const int w = tid >> 6, lane = tid & 63;

  if (DIN_NEXT > 0) stage_weights(sW, W_ru, TB, w, lane);  // async

  int b0, i;
  decode_block(blockIdx.x, w, b0, i);
  const int bi0 = (b0 << 9) + i, bi1 = bi0 + NN;

  float hn0 = 0.f, hn1 = 0.f;
  if (UPD) {
    const float* __restrict__ hcb0 = h_c + ((size_t)b0 << 15);
    const float* __restrict__ dcb0 = dst_c + (b0 << 9);
    const int c_ = cnt[i];
    const int j0 = idx[(i << 7) + lane];
    const int j1 = idx[(i << 7) + 64 + lane];
    const float si0 = src_c[bi0], si1 = src_c[bi1];
    float e00 = -1e30f, e01 = -1e30f, e10 = -1e30f, e11 = -1e30f;
    if (lane < c_) {
      float t0 = si0 + dcb0[j0];      e00 = t0 >= 0.f ? t0 : 0.2f * t0;
      float t1 = si1 + dcb0[NN + j0]; e10 = t1 >= 0.f ? t1 : 0.2f * t1;
    }
    if (lane + 64 < c_) {
      float t0 = si0 + dcb0[j1];      e01 = t0 >= 0.f ? t0 : 0.2f * t0;
      float t1 = si1 + dcb0[NN + j1]; e11 = t1 >= 0.f ? t1 : 0.2f * t1;
    }
    float m0 = fmaxf(e00, e01), m1 = fmaxf(e10, e11);
    wave_max2(m0, m1);
    float p00 = (lane < c_)      ? __expf(e00 - m0) : 0.f;
    float p01 = (lane + 64 < c_) ? __expf(e01 - m0) : 0.f;
    float p10 = (lane < c_)      ? __expf(e10 - m1) : 0.f;
    float p11 = (lane + 64 < c_) ? __expf(e11 - m1) : 0.f;
    float s0 = p00 + p01, s1 = p10 + p11;
    wave_sum2(s0, s1);
    float inv0 = fast_rcp(s0), inv1 = fast_rcp(s1);
    p00 *= inv0; p01 *= inv0; p10 *= inv1; p11 *= inv1;

    float A0 = 0.f, B0 = 0.f, A1 = 0.f, B1 = 0.f;
    const int ccn = (c_ + 7) & ~7;
    for (int base = 0; base < ccn; base += 8) {
      float hv0[8], hv1[8];
      #pragma unroll
      for (int q = 0; q < 8; ++q) {
        int jj = base + q; int sl = jj & 63;
        int j = (jj < 64) ? rlane_i(j0, sl) : rlane_i(j1, sl);
        const float* p = hcb0 + (j << 6) + lane;
        hv0[q] = *p;
        hv1[q] = *(p + (1 << 15));
      }
      #pragma unroll
      for (int q = 0; q < 8; ++q) {
        int jj = base + q; int sl = jj & 63;
        float pv0 = (jj < 64) ? rlane(p00, sl) : rlane(p01, sl);
        float pv1 = (jj < 64) ? rlane(p10, sl) : rlane(p11, sl);
        if (q & 1) { B0 = fmaf(pv0, hv0[q], B0); B1 = fmaf(pv1, hv1[q], B1); }
        else       { A0 = fmaf(pv0, hv0[q], A0); A1 = fmaf(pv1, hv1[q], A1); }
      }
    }
    A0 += B0; A1 += B1;
    const float bc = b_c[lane];
    const float cc0 = tanh_f(A0 + bc), cc1 = tanh_f(A1 + bc);
    const float u0 = u_buf[((size_t)bi0 << 6) + lane];
    const float u1 = u_buf[((size_t)bi1 << 6) + lane];
    const float ho0 = h[((size_t)bi0 << 6) + lane];
    const float ho1 = h[((size_t)bi1 << 6) + lane];
    hn0 = fmaf(u0, ho0 - cc0, cc0);
    hn1 = fmaf(u1, ho1 - cc1, cc1);
  }
  h[((size_t)bi0 << 6) + lane] = hn0;
  h[((size_t)bi1 << 6) + lane] = hn1;
  sh[(w << 7) + lane] = hn0;
  sh[(w << 7) + 64 + lane] = hn1;

  float y0 = 0.f, y1 = 0.f;
  if (OUT) {
    float t0 = hn0 * proj_W[lane];
    float t1 = hn1 * proj_W[lane];
    wave_sum2(t0, t1);
    y0 = t0 + proj_b[0];
    y1 = t1 + proj_b[0];
    if (lane == 0) {
      out_slice[bi0] = y0; y_buf[bi0] = y0;
      out_slice[bi1] = y1; y_buf[bi1] = y1;
    }
  }

  if (DIN_NEXT > 0) {
    __syncthreads();   // drains async weight stage; sh is wave-private
    const int g0 = lane << 1;
    float a00, a01, a10, a11;
    if (XMODE == 0) {
      if (DIN_NEXT == 2) {
        float2 xv0 = *(const float2*)(x_ptr + ((size_t)bi0 << 1));
        float2 xv1 = *(const float2*)(x_ptr + ((size_t)bi1 << 1));
        a00 = xv0.x * sW[g0]; a01 = xv0.x * sW[g0 + 1];
        a00 = fmaf(xv0.y, sW[128 + g0], a00); a01 = fmaf(xv0.y, sW[128 + g0 + 1], a01);
        a10 = xv1.x * sW[g0]; a11 = xv1.x * sW[g0 + 1];
        a10 = fmaf(xv1.y, sW[128 + g0], a10); a11 = fmaf(xv1.y, sW[128 + g0 + 1], a11);
      } else {
        float xv0 = x_ptr[bi0], xv1 = x_ptr[bi1];
        a00 = xv0 * sW[g0]; a01 = xv0 * sW[g0 + 1];
        a10 = xv1 * sW[g0]; a11 = xv1 * sW[g0 + 1];
      }
    } else if (XMODE == 2) {
      a00 = y0 * sW[g0]; a01 = y0 * sW[g0 + 1];
      a10 = y1 * sW[g0]; a11 = y1 * sW[g0 + 1];
    } else {  // XMODE==1: decoder GO token (zeros)
      a00 = 0.f; a01 = 0.f; a10 = 0.f; a11 = 0.f;
    }
    const float* __restrict__ sWh = sW + DIN_NEXT * 128;
    const float* shw0 = sh + (w << 7);
    const float* shw1 = shw0 + 64;
    #pragma unroll
    for (int f2 = 0; f2 < 32; ++f2) {
      float2 hp0 = *(const float2*)(shw0 + 2 * f2);
      float2 hp1 = *(const float2*)(shw1 + 2 * f2);
      float2 w0 = *(const float2*)(sWh + (2 * f2) * 128 + g0);
      float2 w1 = *(const float2*)(sWh + (2 * f2 + 1) * 128 + g0);
      a00 = fmaf(hp0.x, w0.x, a00); a01 = fmaf(hp0.x, w0.y, a01);
      a00 = fmaf(hp0.y, w1.x, a00); a01 = fmaf(hp0.y, w1.y, a01);
      a10 = fmaf(hp1.x, w0.x, a10); a11 = fmaf(hp1.x, w0.y, a11);
      a10 = fmaf(hp1.y, w1.x, a10); a11 = fmaf(hp1.y, w1.y, a11);
    }
    *(float2*)(h_ru + ((size_t)bi0 << 7) + g0) = make_float2(a00, a01);
    *(float2*)(h_ru + ((size_t)bi1 << 7) + g0) = make_float2(a10, a11);
    const float2 ar0 = *(const float2*)(a_ru + g0);
    const float2 ar1 = *(const float2*)(a_ru + 128 + g0);
    float s00 = a00 * ar0.x + a01 * ar0.y;
    float s01 = a00 * ar1.x + a01 * ar1.y;
    float s10 = a10 * ar0.x + a11 * ar0.y;
    float s11 = a10 * ar1.x + a11 * ar1.y;
    wave_sum4(s00, s01, s10, s11);
    if (lane == 0) {
      src_ru[bi0] = s00; dst_ru[bi0] = s01;
      src_ru[bi1] = s10; dst_ru[bi1] = s11;
    }
  }
}

extern "C" void kernel_launch(void* const* d_in, const int* in_sizes, int n_in,
                              void* d_out, int out_size, void* d_ws, size_t ws_size,
                              hipStream_t stream) {
  (void)in_sizes; (void)n_in; (void)out_size; (void)ws_size;
  const float* inputs   = (const float*)d_in[0];
  const float* adj      = (const float*)d_in[1];
  const float* enc_W_ru = (const float*)d_in[2];
  const float* enc_a_ru = (const float*)d_in[3];
  const float* enc_b_ru = (const float*)d_in[4];
  const float* enc_W_c  = (const float*)d_in[5];
  const float* enc_a_c  = (const float*)d_in[6];
  const float* enc_b_c  = (const float*)d_in[7];
  const float* dec_W_ru = (const float*)d_in[8];
  const float* dec_a_ru = (const float*)d_in[9];
  const float* dec_b_ru = (const float*)d_in[10];
  const float* dec_W_c  = (const float*)d_in[11];
  const float* dec_a_c  = (const float*)d_in[12];
  const float* dec_b_c  = (const float*)d_in[13];
  const float* proj_W   = (const float*)d_in[14];
  const float* proj_b   = (const float*)d_in[15];
  float* out = (float*)d_out;

  char* ws = (char*)d_ws;
  int*   cnt    = (int*)ws;                    // 512*4        = 2048
  int*   idx    = (int*)(ws + 2048);           // 512*128*4    = 262144
  float* h      = (float*)(ws + 264192);       // 16*512*64*4  = 2097152
  float* h_ru   = (float*)(ws + 2361344);      // 16*512*128*4 = 4194304
  float* src_ru = (float*)(ws + 6555648);      // 32768
  float* dst_ru = (float*)(ws + 6588416);      // 32768
  float* h_c    = (float*)(ws + 6621184);      // 2097152
  float* src_c  = (float*)(ws + 8718336);      // 32768
  float* dst_c  = (float*)(ws + 8751104);      // 32768
  float* u_buf  = (float*)(ws + 8783872);      // 2097152
  float* y_buf  = (float*)(ws + 10881024);     // 32768 (end 10913792)

  hipMemsetAsync(y_buf, 0, NB * NN * sizeof(float), stream);
  k_adj<<<NN, 64, 0, stream>>>(adj, cnt, idx);

  const int GRID = (NB * NN) / (WPB * 2);  // 512 blocks: wave = node x batch-pair

  // init: h = 0, compute h_ru(x_0) with encoder weights
  k_phaseA<0, 2, 0, 0><<<GRID, 512, 0, stream>>>(cnt, idx, h_c, src_c, dst_c,
      enc_b_c, u_buf, h, proj_W, proj_b, nullptr, y_buf,
      inputs, enc_W_ru, enc_a_ru, h_ru, src_ru, dst_ru);

  for (int t = 0; t < 12; ++t) {
    k_phaseB<2><<<GRID, 512, 0, stream>>>(cnt, idx, h_ru, src_ru, dst_ru, enc_b_ru,
        h, inputs + (size_t)t * NB * NN * 2, enc_W_c, enc_a_c,
        h_c, src_c, dst_c, u_buf);
    if (t < 11)
      k_phaseA<1, 2, 0, 0><<<GRID, 512, 0, stream>>>(cnt, idx, h_c, src_c, dst_c,
          enc_b_c, u_buf, h, proj_W, proj_b, nullptr, y_buf,
          inputs + (size_t)(t + 1) * NB * NN * 2, enc_W_ru, enc_a_ru,
          h_ru, src_ru, dst_ru);
    else  // last encoder cell: prepare decoder cell 0 (x = GO = zeros)
      k_phaseA<1, 1, 1, 0><<<GRID, 512, 0, stream>>>(cnt, idx, h_c, src_c, dst_c,
          enc_b_c, u_buf, h, proj_W, proj_b, nullptr, y_buf,
          nullptr, dec_W_ru, dec_a_ru, h_ru, src_ru, dst_ru);
  }

  for (int k = 0; k < 12; ++k) {
    k_phaseB<1><<<GRID, 512, 0, stream>>>(cnt, idx, h_ru, src_ru, dst_ru, dec_b_ru,
        h, y_buf, dec_W_c, dec_a_c, h_c, src_c, dst_c, u_buf);
    if (k < 11)
      k_phaseA<1, 1, 2, 1><<<GRID, 512, 0, stream>>>(cnt, idx, h_c, src_c, dst_c,
          dec_b_c, u_buf, h, proj_W, proj_b, out + (size_t)k * NB * NN, y_buf,
          nullptr, dec_W_ru, dec_a_ru, h_ru, src_ru, dst_ru);
    else
      k_phaseA<1, 0, 1, 1><<<GRID, 512, 0, stream>>>(cnt, idx, h_c, src_c, dst_c,
          dec_b_c, u_buf, h, proj_W, proj_b, out + (size_t)k * NB * NN, y_buf,
          nullptr, dec_W_ru, dec_a_ru, h_ru, src_ru, dst_ru);
  }
}

// Round 9
// 802.195 us; speedup vs baseline: 1.2169x; 1.2169x over previous
//
#include <hip/hip_runtime.h>
#include <math.h>

// GARNN: graph-attention GRU, B=16, N=512, U=64, SEQ=12, HORIZON=12, all f32.
// R9 = R7 (XCD swizzle, 802us best) with ONE change: k_phaseA launch_bounds
// (512,6)->(512,8). phaseA's natural VGPR is ~52-60 (scalar hv[16] gather, R1
// measured 52) so the 64-VGPR cap is not binding -> 4 blocks/CU = 32 waves/CU,
// single-round residency (was 3+1 two-round). phaseB stays (512,6): its float2
// gather naturally needs >64 VGPR and collapses under the cap (R6: VGPR=32).

#define NB 16
#define NN 512
#define NU 64
#define CAP 128   // neighbor-list capacity (Bin(511,0.1) max << 128)
#define WPB 8     // waves (=nodes) per block

#define AS1 __attribute__((address_space(1)))
#define AS3 __attribute__((address_space(3)))

__device__ __forceinline__ void ld_lds16(float* lds_uniform, const float* g_perlane) {
#if __has_builtin(__builtin_amdgcn_global_load_lds)
  __builtin_amdgcn_global_load_lds((const AS1 unsigned int*)g_perlane,
                                   (AS3 unsigned int*)lds_uniform, 16, 0, 0);
#else
  int lane = threadIdx.x & 63;
  *(float4*)(lds_uniform + lane * 4) = *(const float4*)(g_perlane);
#endif
}

// Async-stage TB bytes of weights into sW. Wave w handles chunks c = w, w+8, ...
__device__ __forceinline__ void stage_weights(float* sW, const float* W, int TB,
                                              int w, int lane) {
  for (int c = w; c * 1024 < TB; c += WPB) {
    int off = c * 1024 + lane * 16;
    if (off < TB)
      ld_lds16((float*)((char*)sW + c * 1024), (const float*)((const char*)W + off));
  }
}

__device__ __forceinline__ float rlane(float v, int l) {
  return __int_as_float(__builtin_amdgcn_readlane(__float_as_int(v), l));
}
__device__ __forceinline__ int rlane_i(int v, int l) {
  return __builtin_amdgcn_readlane(v, l);
}
__device__ __forceinline__ float wave_max(float v) {
  #pragma unroll
  for (int s = 1; s < 64; s <<= 1) v = fmaxf(v, __shfl_xor(v, s));
  return v;
}
__device__ __forceinline__ float wave_sum(float v) {
  #pragma unroll
  for (int s = 1; s < 64; s <<= 1) v += __shfl_xor(v, s);
  return v;
}
__device__ __forceinline__ void wave_sum2(float& x, float& y) {
  #pragma unroll
  for (int s = 1; s < 64; s <<= 1) { x += __shfl_xor(x, s); y += __shfl_xor(y, s); }
}
__device__ __forceinline__ float fast_rcp(float x) {
#if __has_builtin(__builtin_amdgcn_rcpf)
  return __builtin_amdgcn_rcpf(x);
#else
  return 1.0f / x;
#endif
}
__device__ __forceinline__ float sigmoid_f(float x) {
  return fast_rcp(1.0f + __expf(-x));
}
__device__ __forceinline__ float tanh_f(float x) {
  return 1.0f - 2.0f * fast_rcp(__expf(2.0f * x) + 1.0f);
}

// XCD-aware decode: blockIdx%8 selects XCD (dispatch heuristic). Give XCD x
// batches {2x, 2x+1}; k>>6 picks which, k&63 is the node-chunk. Bijective over
// 1024 blocks. Perf-only heuristic: wrong mapping costs speed, not correctness.
__device__ __forceinline__ void decode_block(int bx, int w, int& b, int& i) {
  int x = bx & 7, k = bx >> 3;
  b = (x << 1) | (k >> 6);
  i = ((k & 63) << 3) | w;
}

// Neighbor lists: mask[i][j] = adj[i][j] > 0.9 || i == j, ascending j.
// Pad tail [cnt, CAP) with j=i so gather loops run unpredicated (p=0 there).
__global__ __launch_bounds__(64) void k_adj(const float* __restrict__ adj,
                                            int* __restrict__ cnt,
                                            int* __restrict__ idx) {
  int i = blockIdx.x;
  int l = threadIdx.x;
  int base = 0;
  #pragma unroll
  for (int c = 0; c < 8; ++c) {
    int j = c * 64 + l;
    bool pred = (adj[i * NN + j] > 0.9f) || (j == i);
    unsigned long long m = __ballot(pred);
    int pos = base + __popcll(m & ((1ull << l) - 1ull));
    if (pred && pos < CAP) idx[i * CAP + pos] = j;
    base += __popcll(m);
  }
  int total = base > CAP ? CAP : base;
  for (int p = total + l; p < CAP; p += 64) idx[i * CAP + p] = i;  // pad
  if (l == 0) cnt[i] = total;
}

// Phase B: ru-attention -> r,u ; write u; h_c = [x, r*h] @ W_c; src_c/dst_c.
template <int DIN>
__global__ __launch_bounds__(512, 6) void k_phaseB(
    const int* __restrict__ cnt, const int* __restrict__ idx,
    const float* __restrict__ h_ru, const float* __restrict__ src_ru,
    const float* __restrict__ dst_ru, const float* __restrict__ b_ru,
    const float* __restrict__ h, const float* __restrict__ x_ptr,
    const float* __restrict__ W_c, const float* __restrict__ a_c,
    float* __restrict__ h_c, float* __restrict__ src_c,
    float* __restrict__ dst_c, float* __restrict__ u_buf) {
  constexpr int TB = (DIN + NU) * NU * 4;
  __shared__ float sW[(DIN + NU) * NU];
  __shared__ float sh[WPB * NU];    // per-wave r*h broadcast
  const int tid = threadIdx.x;
  const int w = tid >> 6, lane = tid & 63;

  stage_weights(sW, W_c, TB, w, lane);   // async; drained at the barrier below

  int b, i;
  decode_block(blockIdx.x, w, b, i);
  const int base_bi = (b << 9) + i;
  const float* __restrict__ hrb = h_ru + ((size_t)b << 16);
  const float* __restrict__ drb = dst_ru + (b << 9);

  const int c_ = cnt[i];
  const float si = src_ru[base_bi];
  const int j0 = idx[(i << 7) + lane];
  const int j1 = idx[(i << 7) + 64 + lane];
  float e0 = -1e30f, e1 = -1e30f;
  if (lane < c_)      { float t = si + drb[j0]; e0 = t >= 0.f ? t : 0.2f * t; }
  if (lane + 64 < c_) { float t = si + drb[j1]; e1 = t >= 0.f ? t : 0.2f * t; }
  float m = wave_max(fmaxf(e0, e1));
  float p0 = (lane < c_) ? __expf(e0 - m) : 0.f;
  float p1 = (lane + 64 < c_) ? __expf(e1 - m) : 0.f;
  float inv = fast_rcp(wave_sum(p0 + p1));
  p0 *= inv; p1 *= inv;

  // aggregation: ru[g] over neighbors, g = 2*lane, 2*lane+1.
  // 16-deep register prefetch: 16 independent loads in flight per group.
  const int g0 = lane << 1;
  float A0 = 0.f, A1 = 0.f, B0 = 0.f, B1 = 0.f;
  const int cc = (c_ + 15) & ~15;
  for (int base = 0; base < cc; base += 16) {
    float2 hv[16];
    #pragma unroll
    for (int q = 0; q < 16; ++q) {
      int jj = base + q;
      int sl = jj & 63;
      int j = (jj < 64) ? rlane_i(j0, sl) : rlane_i(j1, sl);
      hv[q] = *(const float2*)(hrb + (j << 7) + g0);
    }
    #pragma unroll
    for (int q = 0; q < 16; ++q) {
      int jj = base + q;
      int sl = jj & 63;
      float pv = (jj < 64) ? rlane(p0, sl) : rlane(p1, sl);
      if (q & 1) { B0 = fmaf(pv, hv[q].x, B0); B1 = fmaf(pv, hv[q].y, B1); }
      else       { A0 = fmaf(pv, hv[q].x, A0); A1 = fmaf(pv, hv[q].y, A1); }
    }
  }
  A0 += B0; A1 += B1;

  const float2 br = *(const float2*)(b_ru + g0);
  const float ru0 = sigmoid_f(A0 + br.x);
  const float ru1 = sigmoid_f(A1 + br.y);

  // lanes 0..31: r (g<64) -> r*h into LDS; lanes 32..63: u -> global
  if (lane < 32) {
    float2 hh = *(const float2*)(h + ((size_t)base_bi << 6) + g0);
    *(float2*)&sh[(w << 6) + g0] = make_float2(ru0 * hh.x, ru1 * hh.y);
  } else {
    *(float2*)(u_buf + ((size_t)base_bi << 6) + (g0 - 64)) = make_float2(ru0, ru1);
  }

  __syncthreads();   // drains async weight stage + sh visibility

  // h_c GEMV over xc = [x, r*h]; output feature = lane
  float acc;
  if (DIN == 2) {
    float2 xv = *(const float2*)(x_ptr + ((size_t)base_bi << 1));
    acc = xv.x * sW[lane];
    acc = fmaf(xv.y, sW[NU + lane], acc);
  } else {
    acc = x_ptr[base_bi] * sW[lane];
  }
  const float* __restrict__ sWh = sW + DIN * NU;
  const float* shw = sh + (w << 6);
  #pragma unroll
  for (int f2 = 0; f2 < 32; ++f2) {
    float2 rv = *(const float2*)(shw + 2 * f2);   // b64 broadcast
    acc = fmaf(rv.x, sWh[(2 * f2) * NU + lane], acc);
    acc = fmaf(rv.y, sWh[(2 * f2 + 1) * NU + lane], acc);
  }
  h_c[((size_t)base_bi << 6) + lane] = acc;
  float s0 = acc * a_c[lane];
  float s1 = acc * a_c[NU + lane];
  wave_sum2(s0, s1);
  if (lane == 0) { src_c[base_bi] = s0; dst_c[base_bi] = s1; }
}

// Phase A: c-attention -> c; h_new = u*h + (1-u)*c (UPD) or 0 (init);
// OUT: proj -> out+y_buf; DIN_NEXT>0: next cell h_ru = [x_next, h_new] @ W_ru.
// (512,8): natural VGPR ~52-60 fits the 64 cap -> 4 blocks/CU, single round.
template <int UPD, int DIN_NEXT, int XMODE, int OUT>
__global__ __launch_bounds__(512, 8) void k_phaseA(
    const int* __restrict__ cnt, const int* __restrict__ idx,
    const float* __restrict__ h_c, const float* __restrict__ src_c,
    const float* __restrict__ dst_c, const float* __restrict__ b_c,
    const float* __restrict__ u_buf, float* __restrict__ h,
    const float* __restrict__ proj_W, const float* __restrict__ proj_b,
    float* __restrict__ out_slice, float* __restrict__ y_buf,
    const float* __restrict__ x_ptr,
    const float* __restrict__ W_ru, const float* __restrict__ a_ru,
    float* __restrict__ h_ru, float* __restrict__ src_ru,
    float* __restrict__ dst_ru) {
  constexpr int SWN = (DIN_NEXT > 0) ? (DIN_NEXT + NU) * 128 : 1;
  constexpr int TB = (DIN_NEXT > 0) ? SWN * 4 : 0;
  __shared__ float sW[SWN];
  __shared__ float sh[WPB * NU];
  const int tid = threadIdx.x;
  const int w = tid >> 6, lane = tid & 63;

  if (DIN_NEXT > 0) stage_weights(sW, W_ru, TB, w, lane);  // async

  int b, i;
  decode_block(blockIdx.x, w, b, i);
  const int base_bi = (b << 9) + i;

  float hn = 0.f;
  if (UPD) {
    const float* __restrict__ hcb = h_c + ((size_t)b << 15);
    const float* __restrict__ dcb = dst_c + (b << 9);
    const int c_ = cnt[i];
    const float si = src_c[base_bi];
    const int j0 = idx[(i << 7) + lane];
    const int j1 = idx[(i << 7) + 64 + lane];
    float e0 = -1e30f, e1 = -1e30f;
    if (lane < c_)      { float t = si + dcb[j0]; e0 = t >= 0.f ? t : 0.2f * t; }
    if (lane + 64 < c_) { float t = si + dcb[j1]; e1 = t >= 0.f ? t : 0.2f * t; }
    float m = wave_max(fmaxf(e0, e1));
    float p0 = (lane < c_) ? __expf(e0 - m) : 0.f;
    float p1 = (lane + 64 < c_) ? __expf(e1 - m) : 0.f;
    float inv = fast_rcp(wave_sum(p0 + p1));
    p0 *= inv; p1 *= inv;

    float A = 0.f, Bacc = 0.f;
    const int cc = (c_ + 15) & ~15;
    for (int base = 0; base < cc; base += 16) {
      float hv[16];
      #pragma unroll
      for (int q = 0; q < 16; ++q) {
        int jj = base + q;
        int sl = jj & 63;
        int j = (jj < 64) ? rlane_i(j0, sl) : rlane_i(j1, sl);
        hv[q] = hcb[(j << 6) + lane];
      }
      #pragma unroll
      for (int q = 0; q < 16; ++q) {
        int jj = base + q;
        int sl = jj & 63;
        float pv = (jj < 64) ? rlane(p0, sl) : rlane(p1, sl);
        if (q & 1) Bacc = fmaf(pv, hv[q], Bacc);
        else       A = fmaf(pv, hv[q], A);
      }
    }
    A += Bacc;
    const float cc_ = tanh_f(A + b_c[lane]);
    const float u = u_buf[((size_t)base_bi << 6) + lane];
    const float ho = h[((size_t)base_bi << 6) + lane];
    hn = fmaf(u, ho - cc_, cc_);   // u*ho + (1-u)*cc
  }
  h[((size_t)base_bi << 6) + lane] = hn;
  sh[(w << 6) + lane] = hn;        // wave-private broadcast buffer

  float y = 0.f;
  if (OUT) {
    float t = wave_sum(hn * proj_W[lane]);
    y = t + proj_b[0];
    if (lane == 0) { out_slice[base_bi] = y; y_buf[base_bi] = y; }
  }

  if (DIN_NEXT > 0) {
    __syncthreads();   // drains async weight stage; sh written above
    const int g0 = lane << 1;
    float a0, a1;
    if (XMODE == 0) {
      if (DIN_NEXT == 2) {
        float2 xv = *(const float2*)(x_ptr + ((size_t)base_bi << 1));
        a0 = xv.x * sW[g0];
        a1 = xv.x * sW[g0 + 1];
        a0 = fmaf(xv.y, sW[128 + g0], a0);
        a1 = fmaf(xv.y, sW[128 + g0 + 1], a1);
      } else {
        float xv = x_ptr[base_bi];
        a0 = xv * sW[g0]; a1 = xv * sW[g0 + 1];
      }
    } else if (XMODE == 2) {
      a0 = y * sW[g0]; a1 = y * sW[g0 + 1];
    } else {  // XMODE==1: decoder GO token (zeros)
      a0 = 0.f; a1 = 0.f;
    }
    const float* __restrict__ sWh = sW + DIN_NEXT * 128;
    const float* shw = sh + (w << 6);
    #pragma unroll
    for (int f2 = 0; f2 < 32; ++f2) {
      float2 hp = *(const float2*)(shw + 2 * f2);          // b64 broadcast
      float2 w0 = *(const float2*)(sWh + (2 * f2) * 128 + g0);
      float2 w1 = *(const float2*)(sWh + (2 * f2 + 1) * 128 + g0);
      a0 = fmaf(hp.x, w0.x, a0); a1 = fmaf(hp.x, w0.y, a1);
      a0 = fmaf(hp.y, w1.x, a0); a1 = fmaf(hp.y, w1.y, a1);
    }
    *(float2*)(h_ru + ((size_t)base_bi << 7) + g0) = make_float2(a0, a1);
    const float2 ar0 = *(const float2*)(a_ru + g0);
    const float2 ar1 = *(const float2*)(a_ru + 128 + g0);
    float s0 = a0 * ar0.x + a1 * ar0.y;
    float s1 = a0 * ar1.x + a1 * ar1.y;
    wave_sum2(s0, s1);
    if (lane == 0) { src_ru[base_bi] = s0; dst_ru[base_bi] = s1; }
  }
}

extern "C" void kernel_launch(void* const* d_in, const int* in_sizes, int n_in,
                              void* d_out, int out_size, void* d_ws, size_t ws_size,
                              hipStream_t stream) {
  (void)in_sizes; (void)n_in; (void)out_size; (void)ws_size;
  const float* inputs   = (const float*)d_in[0];
  const float* adj      = (const float*)d_in[1];
  const float* enc_W_ru = (const float*)d_in[2];
  const float* enc_a_ru = (const float*)d_in[3];
  const float* enc_b_ru = (const float*)d_in[4];
  const float* enc_W_c  = (const float*)d_in[5];
  const float* enc_a_c  = (const float*)d_in[6];
  const float* enc_b_c  = (const float*)d_in[7];
  const float* dec_W_ru = (const float*)d_in[8];
  const float* dec_a_ru = (const float*)d_in[9];
  const float* dec_b_ru = (const float*)d_in[10];
  const float* dec_W_c  = (const float*)d_in[11];
  const float* dec_a_c  = (const float*)d_in[12];
  const float* dec_b_c  = (const float*)d_in[13];
  const float* proj_W   = (const float*)d_in[14];
  const float* proj_b   = (const float*)d_in[15];
  float* out = (float*)d_out;

  char* ws = (char*)d_ws;
  int*   cnt    = (int*)ws;                    // 512*4        = 2048
  int*   idx    = (int*)(ws + 2048);           // 512*128*4    = 262144
  float* h      = (float*)(ws + 264192);       // 16*512*64*4  = 2097152
  float* h_ru   = (float*)(ws + 2361344);      // 16*512*128*4 = 4194304
  float* src_ru = (float*)(ws + 6555648);      // 32768
  float* dst_ru = (float*)(ws + 6588416);      // 32768
  float* h_c    = (float*)(ws + 6621184);      // 2097152
  float* src_c  = (float*)(ws + 8718336);      // 32768
  float* dst_c  = (float*)(ws + 8751104);      // 32768
  float* u_buf  = (float*)(ws + 8783872);      // 2097152
  float* y_buf  = (float*)(ws + 10881024);     // 32768 (end 10913792)

  hipMemsetAsync(y_buf, 0, NB * NN * sizeof(float), stream);
  k_adj<<<NN, 64, 0, stream>>>(adj, cnt, idx);

  const int GRID = (NB * NN) / WPB;  // 1024 blocks, 8 waves/block, 1 node/wave

  // init: h = 0, compute h_ru(x_0) with encoder weights
  k_phaseA<0, 2, 0, 0><<<GRID, 512, 0, stream>>>(cnt, idx, h_c, src_c, dst_c,
      enc_b_c, u_buf, h, proj_W, proj_b, nullptr, y_buf,
      inputs, enc_W_ru, enc_a_ru, h_ru, src_ru, dst_ru);

  for (int t = 0; t < 12; ++t) {
    k_phaseB<2><<<GRID, 512, 0, stream>>>(cnt, idx, h_ru, src_ru, dst_ru, enc_b_ru,
        h, inputs + (size_t)t * NB * NN * 2, enc_W_c, enc_a_c,
        h_c, src_c, dst_c, u_buf);
    if (t < 11)
      k_phaseA<1, 2, 0, 0><<<GRID, 512, 0, stream>>>(cnt, idx, h_c, src_c, dst_c,
          enc_b_c, u_buf, h, proj_W, proj_b, nullptr, y_buf,
          inputs + (size_t)(t + 1) * NB * NN * 2, enc_W_ru, enc_a_ru,
          h_ru, src_ru, dst_ru);
    else  // last encoder cell: prepare decoder cell 0 (x = GO = zeros)
      k_phaseA<1, 1, 1, 0><<<GRID, 512, 0, stream>>>(cnt, idx, h_c, src_c, dst_c,
          enc_b_c, u_buf, h, proj_W, proj_b, nullptr, y_buf,
          nullptr, dec_W_ru, dec_a_ru, h_ru, src_ru, dst_ru);
  }

  for (int k = 0; k < 12; ++k) {
    k_phaseB<1><<<GRID, 512, 0, stream>>>(cnt, idx, h_ru, src_ru, dst_ru, dec_b_ru,
        h, y_buf, dec_W_c, dec_a_c, h_c, src_c, dst_c, u_buf);
    if (k < 11)
      k_phaseA<1, 1, 2, 1><<<GRID, 512, 0, stream>>>(cnt, idx, h_c, src_c, dst_c,
          dec_b_c, u_buf, h, proj_W, proj_b, out + (size_t)k * NB * NN, y_buf,
          nullptr, dec_W_ru, dec_a_ru, h_ru, src_ru, dst_ru);
    else
      k_phaseA<1, 0, 1, 1><<<GRID, 512, 0, stream>>>(cnt, idx, h_c, src_c, dst_c,
          dec_b_c, u_buf, h, proj_W, proj_b, out + (size_t)k * NB * NN, y_buf,
          nullptr, dec_W_ru, dec_a_ru, h_ru, src_ru, dst_ru);
  }
}